// Round 2
// baseline (6507.623 us; speedup 1.0000x reference)
//
#include <hip/hip_runtime.h>
#include <hip/hip_bf16.h>

#define T_TOK 3600
#define D_    512
#define H_    8
#define HD    64
#define FF_   2048
#define NKT   57   // ceil(3600/64)

// timestep of token index: players [0,3000) step i/10, ball [3000,3300), cls [3300,3600)
__device__ __forceinline__ int step_of(int i) {
    return (i < 3000) ? (i / 10) : ((i < 3300) ? (i - 3000) : (i - 3300));
}

// ---------------- token embedding MLPs -------------------------------------
__global__ __launch_bounds__(256) void token_kernel(
    const float* __restrict__ pxs, const float* __restrict__ pys, const float* __restrict__ phs,
    const float* __restrict__ bxs, const float* __restrict__ bys, const float* __restrict__ bzs,
    const float* __restrict__ emb_table, const float* __restrict__ ball_emb,
    const float* __restrict__ cls_emb,
    const float* __restrict__ pW0, const float* __restrict__ pb0,
    const float* __restrict__ pW1, const float* __restrict__ pb1,
    const float* __restrict__ pW2, const float* __restrict__ pb2,
    const float* __restrict__ bW0, const float* __restrict__ bb0,
    const float* __restrict__ bW1, const float* __restrict__ bb1,
    const float* __restrict__ bW2, const float* __restrict__ bb2,
    const int* __restrict__ pidx, float* __restrict__ x)
{
    int tok = blockIdx.x;
    int t = threadIdx.x;
    if (tok >= 3300) { // cls rows: broadcast, NOT scaled
        x[(size_t)tok * D_ + t]       = cls_emb[t];
        x[(size_t)tok * D_ + t + 256] = cls_emb[t + 256];
        return;
    }
    __shared__ float in[24];
    __shared__ float h0[128];
    __shared__ float h1[256];
    bool isP = tok < 3000;
    const float *W0 = isP ? pW0 : bW0, *b0 = isP ? pb0 : bb0;
    const float *W1 = isP ? pW1 : bW1, *b1 = isP ? pb1 : bb1;
    const float *W2 = isP ? pW2 : bW2, *b2 = isP ? pb2 : bb2;
    if (t < 20) {
        if (isP) { int id = pidx[tok]; in[t] = emb_table[id * 20 + t]; }
        else     { in[t] = ball_emb[t]; }
    } else if (t < 23) {
        if (isP) in[t] = (t == 20) ? pxs[tok] : (t == 21) ? pys[tok] : phs[tok];
        else { int b = tok - 3000;
               in[t] = (t == 20) ? bxs[b] : (t == 21) ? bys[b] : bzs[b]; }
    }
    __syncthreads();
    if (t < 128) {
        float s = b0[t];
        const float* wr = W0 + t * 23;
        #pragma unroll
        for (int k = 0; k < 23; k++) s += wr[k] * in[k];
        h0[t] = fmaxf(s, 0.f);
    }
    __syncthreads();
    {
        float s = b1[t];
        const float4* wr4 = reinterpret_cast<const float4*>(W1 + t * 128);
        #pragma unroll 8
        for (int k4 = 0; k4 < 32; k4++) {
            float4 u = wr4[k4];
            s += u.x * h0[k4*4+0] + u.y * h0[k4*4+1]
               + u.z * h0[k4*4+2] + u.w * h0[k4*4+3];
        }
        h1[t] = fmaxf(s, 0.f);
    }
    __syncthreads();
    const float scale = 22.627416997969522f; // sqrt(512)
    for (int j = t; j < D_; j += 256) {
        float s = b2[j];
        const float4* wr4 = reinterpret_cast<const float4*>(W2 + j * 256);
        #pragma unroll 8
        for (int k4 = 0; k4 < 64; k4++) {
            float4 u = wr4[k4];
            s += u.x * h1[k4*4+0] + u.y * h1[k4*4+1]
               + u.z * h1[k4*4+2] + u.w * h1[k4*4+3];
        }
        x[(size_t)tok * D_ + j] = s * scale;
    }
}

// ---------------- fp32 tiled GEMM: C[M,N] = act(A[M,K] * W[N,K]^T + bias) ---
template<int RELU>
__global__ __launch_bounds__(256) void gemm_nt(
    const float* __restrict__ A, const float* __restrict__ W,
    const float* __restrict__ bias,
    float* __restrict__ C,
    int M, int N, int K)
{
    __shared__ float As[16][68]; // [k][m], pad->2-way max conflict on float4 reads
    __shared__ float Ws[16][68]; // [k][n]
    int t = threadIdx.x;
    int tx = t & 15, ty = t >> 4;
    int m0 = blockIdx.x * 64, n0 = blockIdx.y * 64;
    int lm = t >> 2;        // 0..63  (row within tile to load)
    int lk = (t & 3) * 4;   // 0,4,8,12 (k offset, float4)
    float acc[4][4] = {};
    for (int kk = 0; kk < K; kk += 16) {
        {
            int m = m0 + lm;
            float4 v = make_float4(0.f, 0.f, 0.f, 0.f);
            if (m < M) v = *reinterpret_cast<const float4*>(A + (size_t)m * K + kk + lk);
            As[lk + 0][lm] = v.x; As[lk + 1][lm] = v.y;
            As[lk + 2][lm] = v.z; As[lk + 3][lm] = v.w;
        }
        {
            int n = n0 + lm;
            float4 v = make_float4(0.f, 0.f, 0.f, 0.f);
            if (n < N) v = *reinterpret_cast<const float4*>(W + (size_t)n * K + kk + lk);
            Ws[lk + 0][lm] = v.x; Ws[lk + 1][lm] = v.y;
            Ws[lk + 2][lm] = v.z; Ws[lk + 3][lm] = v.w;
        }
        __syncthreads();
        #pragma unroll
        for (int k = 0; k < 16; k++) {
            float4 a = *reinterpret_cast<const float4*>(&As[k][ty * 4]);
            float4 b = *reinterpret_cast<const float4*>(&Ws[k][tx * 4]);
            float av[4] = {a.x, a.y, a.z, a.w};
            float bv[4] = {b.x, b.y, b.z, b.w};
            #pragma unroll
            for (int i = 0; i < 4; i++)
                #pragma unroll
                for (int j = 0; j < 4; j++)
                    acc[i][j] += av[i] * bv[j];
        }
        __syncthreads();
    }
    #pragma unroll
    for (int i = 0; i < 4; i++) {
        int m = m0 + ty * 4 + i;
        if (m >= M) continue;
        #pragma unroll
        for (int j = 0; j < 4; j++) {
            int n = n0 + tx * 4 + j;
            if (n >= N) continue;
            float v = acc[i][j] + bias[n];
            if (RELU) v = fmaxf(v, 0.f);
            C[(size_t)m * N + n] = v;
        }
    }
}

// ---------------- flash attention (fp32), block-causal by timestep ----------
// grid: (57 q-tiles, 8 heads), block: 128 = 2 waves splitting key tiles.
__global__ __launch_bounds__(128) void attn_kernel(
    const float* __restrict__ qkv, float* __restrict__ ob)
{
    __shared__ float smem[16384]; // 64KB: Ks(2x64x64) | Vs(2x64x64); tails reused for merge
    int t = threadIdx.x;
    int w = t >> 6;   // wave
    int l = t & 63;   // lane = query within tile
    float* Ksw = smem + w * 4096;
    float* Vsw = smem + 8192 + w * 4096;

    int q0 = blockIdx.x * 64;
    int h = blockIdx.y;
    int q = q0 + l;
    bool valid = q < T_TOK;
    int sq = valid ? step_of(q) : -1;

    int smax = sq;
    #pragma unroll
    for (int off = 32; off > 0; off >>= 1) smax = max(smax, __shfl_xor(smax, off));

    float qreg[64];
    if (valid) {
        const float* qp = qkv + (size_t)q * (3 * D_) + h * HD;
        #pragma unroll
        for (int k4 = 0; k4 < 16; k4++) {
            float4 v = *reinterpret_cast<const float4*>(qp + k4 * 4);
            qreg[k4*4+0] = v.x; qreg[k4*4+1] = v.y; qreg[k4*4+2] = v.z; qreg[k4*4+3] = v.w;
        }
    } else {
        #pragma unroll
        for (int k = 0; k < 64; k++) qreg[k] = 0.f;
    }
    const float sc = 0.125f; // 1/sqrt(64)
    #pragma unroll
    for (int k = 0; k < 64; k++) qreg[k] *= sc;

    float oacc[64];
    #pragma unroll
    for (int k = 0; k < 64; k++) oacc[k] = 0.f;
    float m = -INFINITY, lsum = 0.f;

    #pragma unroll 1
    for (int kt = w; kt < NKT; kt += 2) {
        int kbase = kt * 64;
        // skip tiles whose minimum step exceeds this block's max query step
        int a = kbase, b = min(kbase + 63, T_TOK - 1);
        int mn = 0x7fffffff;
        if (a < 3000) mn = min(mn, a / 10);
        if (b >= 3000 && a < 3300) mn = min(mn, max(a, 3000) - 3000);
        if (b >= 3300) mn = min(mn, max(a, 3300) - 3300);
        if (mn > smax) continue;

        const float* kp = qkv + (size_t)kbase * (3 * D_) + D_ + h * HD;
        const float* vp = qkv + (size_t)kbase * (3 * D_) + 2 * D_ + h * HD;
        #pragma unroll
        for (int rep = 0; rep < 16; rep++) {
            int j = rep * 4 + (l >> 4);
            int kf = (l & 15) * 4;
            int key = kbase + j;
            float4 kv = make_float4(0.f, 0.f, 0.f, 0.f);
            float4 vv = make_float4(0.f, 0.f, 0.f, 0.f);
            if (key < T_TOK) {
                kv = *reinterpret_cast<const float4*>(kp + (size_t)j * (3 * D_) + kf);
                vv = *reinterpret_cast<const float4*>(vp + (size_t)j * (3 * D_) + kf);
            }
            *reinterpret_cast<float4*>(&Ksw[j * 64 + kf]) = kv;
            *reinterpret_cast<float4*>(&Vsw[j * 64 + kf]) = vv;
        }
        // same-wave LDS RAW: compiler inserts lgkmcnt waits

        #pragma unroll 1
        for (int c = 0; c < 4; c++) {
            float s[16];
            #pragma unroll
            for (int j = 0; j < 16; j++) {
                int jj = c * 16 + j;
                int key = kbase + jj;
                float acc = 0.f;
                #pragma unroll
                for (int k4 = 0; k4 < 16; k4++) {
                    float4 kv = *reinterpret_cast<const float4*>(&Ksw[jj * 64 + k4 * 4]);
                    acc += qreg[k4*4+0] * kv.x + qreg[k4*4+1] * kv.y
                         + qreg[k4*4+2] * kv.z + qreg[k4*4+3] * kv.w;
                }
                bool vis = (key < T_TOK) && (step_of(key) <= sq);
                s[j] = vis ? acc : -INFINITY;
            }
            float mt = s[0];
            #pragma unroll
            for (int j = 1; j < 16; j++) mt = fmaxf(mt, s[j]);
            if (mt == -INFINITY) continue; // fully masked chunk (per-lane)
            if (mt > m) {
                float cc = __expf(m - mt); // m=-inf -> 0
                lsum *= cc;
                #pragma unroll
                for (int k = 0; k < 64; k++) oacc[k] *= cc;
                m = mt;
            }
            #pragma unroll
            for (int j = 0; j < 16; j++) {
                int jj = c * 16 + j;
                float p = __expf(s[j] - m);
                lsum += p;
                #pragma unroll
                for (int k4 = 0; k4 < 16; k4++) {
                    float4 vv = *reinterpret_cast<const float4*>(&Vsw[jj * 64 + k4 * 4]);
                    oacc[k4*4+0] += p * vv.x; oacc[k4*4+1] += p * vv.y;
                    oacc[k4*4+2] += p * vv.z; oacc[k4*4+3] += p * vv.w;
                }
            }
        }
    }
    // publish per-wave state: o -> own Ks region; m,l -> own Vs region head
    #pragma unroll
    for (int k = 0; k < 64; k++) Ksw[l * 64 + k] = oacc[k];
    Vsw[l] = m;
    Vsw[64 + l] = lsum;
    __syncthreads();
    if (w == 0 && valid) {
        float m0 = smem[8192 + l],        m1 = smem[8192 + 4096 + l];
        float l0 = smem[8192 + 64 + l],   l1 = smem[8192 + 4096 + 64 + l];
        float M = fmaxf(m0, m1);
        float c0 = (l0 > 0.f) ? __expf(m0 - M) : 0.f;
        float c1 = (l1 > 0.f) ? __expf(m1 - M) : 0.f;
        float inv = 1.f / (l0 * c0 + l1 * c1);
        float* op = ob + (size_t)q * D_ + h * HD;
        #pragma unroll
        for (int k = 0; k < 64; k++)
            op[k] = (smem[l * 64 + k] * c0 + smem[4096 + l * 64 + k] * c1) * inv;
    }
}

// ---------------- fused residual add + LayerNorm ---------------------------
__global__ __launch_bounds__(256) void add_ln_kernel(
    float* __restrict__ x, const float* __restrict__ r,
    const float* __restrict__ g, const float* __restrict__ b)
{
    int row = blockIdx.x, t = threadIdx.x;
    size_t base = (size_t)row * D_;
    float v0 = x[base + t] + r[base + t];
    float v1 = x[base + t + 256] + r[base + t + 256];
    float s = v0 + v1, ss = v0 * v0 + v1 * v1;
    #pragma unroll
    for (int off = 32; off > 0; off >>= 1) {
        s  += __shfl_xor(s, off);
        ss += __shfl_xor(ss, off);
    }
    __shared__ float rs[4], rss[4];
    int w = t >> 6;
    if ((t & 63) == 0) { rs[w] = s; rss[w] = ss; }
    __syncthreads();
    s  = rs[0] + rs[1] + rs[2] + rs[3];
    ss = rss[0] + rss[1] + rss[2] + rss[3];
    float mean = s * (1.f / 512.f);
    float var = ss * (1.f / 512.f) - mean * mean;
    float rstd = rsqrtf(var + 1e-5f);
    x[base + t]       = (v0 - mean) * rstd * g[t]       + b[t];
    x[base + t + 256] = (v1 - mean) * rstd * g[t + 256] + b[t + 256];
}

// ---------------------------------------------------------------------------
extern "C" void kernel_launch(void* const* d_in, const int* in_sizes, int n_in,
                              void* d_out, int out_size, void* d_ws, size_t ws_size,
                              hipStream_t stream)
{
    const float* player_xs = (const float*)d_in[0];
    const float* player_ys = (const float*)d_in[1];
    const float* player_hs = (const float*)d_in[2];
    const float* ball_xs   = (const float*)d_in[3];
    const float* ball_ys   = (const float*)d_in[4];
    const float* ball_zs   = (const float*)d_in[5];
    const float* emb_table = (const float*)d_in[6];
    const float* ball_emb  = (const float*)d_in[7];
    const float* cls_emb   = (const float*)d_in[8];
    const float* pW0 = (const float*)d_in[9];   const float* pb0 = (const float*)d_in[10];
    const float* pW1 = (const float*)d_in[11];  const float* pb1 = (const float*)d_in[12];
    const float* pW2 = (const float*)d_in[13];  const float* pb2 = (const float*)d_in[14];
    const float* bW0 = (const float*)d_in[15];  const float* bb0 = (const float*)d_in[16];
    const float* bW1 = (const float*)d_in[17];  const float* bb1 = (const float*)d_in[18];
    const float* bW2 = (const float*)d_in[19];  const float* bb2 = (const float*)d_in[20];
    const float* Wqkv = (const float*)d_in[21]; const float* bqkv = (const float*)d_in[22];
    const float* Wo  = (const float*)d_in[23];  const float* bo  = (const float*)d_in[24];
    const float* W1f = (const float*)d_in[25];  const float* b1f = (const float*)d_in[26];
    const float* W2f = (const float*)d_in[27];  const float* b2f = (const float*)d_in[28];
    const float* g1  = (const float*)d_in[29];  const float* be1 = (const float*)d_in[30];
    const float* g2  = (const float*)d_in[31];  const float* be2 = (const float*)d_in[32];
    const float* cpW = (const float*)d_in[33];  const float* cpb = (const float*)d_in[34];
    const float* cbW = (const float*)d_in[35];  const float* cbb = (const float*)d_in[36];
    const float* csW = (const float*)d_in[37];  const float* csb = (const float*)d_in[38];
    const int* pidx = (const int*)d_in[39];

    // workspace (fp32): x | big(qkv/ff1) | o | tmp  = 51.7 MB
    float* x   = (float*)d_ws;            // 3600*512   = 1,843,200
    float* big = x + 1843200;             // 3600*2048  = 7,372,800 (holds qkv 3600*1536 too)
    float* ob  = big + 7372800;           // 3600*512
    float* tmp = ob + 1843200;            // 3600*512
    float* out = (float*)d_out;

    token_kernel<<<3600, 256, 0, stream>>>(
        player_xs, player_ys, player_hs, ball_xs, ball_ys, ball_zs,
        emb_table, ball_emb, cls_emb,
        pW0, pb0, pW1, pb1, pW2, pb2,
        bW0, bb0, bW1, bb1, bW2, bb2, pidx, x);

    for (int l = 0; l < 4; l++) {
        const float* Wqkv_l = Wqkv + (size_t)l * 1536 * 512;
        const float* bqkv_l = bqkv + (size_t)l * 1536;
        const float* Wo_l   = Wo   + (size_t)l * 512 * 512;
        const float* bo_l   = bo   + (size_t)l * 512;
        const float* W1f_l  = W1f  + (size_t)l * 2048 * 512;
        const float* b1f_l  = b1f  + (size_t)l * 2048;
        const float* W2f_l  = W2f  + (size_t)l * 512 * 2048;
        const float* b2f_l  = b2f  + (size_t)l * 512;

        gemm_nt<0><<<dim3(57, 24), 256, 0, stream>>>(x,   Wqkv_l, bqkv_l, big, 3600, 1536, 512);
        attn_kernel<<<dim3(57, 8), 128, 0, stream>>>(big, ob);
        gemm_nt<0><<<dim3(57, 8),  256, 0, stream>>>(ob,  Wo_l,   bo_l,   tmp, 3600, 512,  512);
        add_ln_kernel<<<3600, 256, 0, stream>>>(x, tmp, g1 + (size_t)l * 512, be1 + (size_t)l * 512);
        gemm_nt<1><<<dim3(57, 32), 256, 0, stream>>>(x,   W1f_l,  b1f_l,  big, 3600, 2048, 512);
        gemm_nt<0><<<dim3(57, 8),  256, 0, stream>>>(big, W2f_l,  b2f_l,  tmp, 3600, 512,  2048);
        add_ln_kernel<<<3600, 256, 0, stream>>>(x, tmp, g2 + (size_t)l * 512, be2 + (size_t)l * 512);
    }

    gemm_nt<0><<<dim3(57, 2),  256, 0, stream>>>(x, cpW, cpb, out + 0,       3600, 121,  512);
    gemm_nt<0><<<dim3(57, 21), 256, 0, stream>>>(x, cbW, cbb, out + 435600,  3600, 1331, 512);
    gemm_nt<0><<<dim3(57, 1),  256, 0, stream>>>(x, csW, csb, out + 5227200, 3600, 10,   512);
}